// Round 14
// baseline (414.722 us; speedup 1.0000x reference)
//
#include <hip/hip_runtime.h>

typedef unsigned short ushort_t;
typedef __attribute__((ext_vector_type(8))) short short8;
typedef __attribute__((ext_vector_type(4))) float f32x4;

#define DEV __device__ __forceinline__

constexpr int B_ = 4, T_ = 2048, D_ = 1024, H_ = 16;
constexpr int M_ = B_ * T_;                 // 8192 rows
constexpr float LOG2E_ = 1.4426950408889634f;

DEV ushort_t f2bf(float f) {
  union { float f; unsigned u; } c; c.f = f;
  unsigned u = c.u;
  return (ushort_t)((u + 0x7fffu + ((u >> 16) & 1u)) >> 16);
}
DEV float bf2f(ushort_t b) {
  union { unsigned u; float f; } c; c.u = ((unsigned)b) << 16;
  return c.f;
}
DEV unsigned cvt_pk_bf16(float lo, float hi) {
  unsigned r;
  asm("v_cvt_pk_bf16_f32 %0, %1, %2" : "=v"(r) : "v"(lo), "v"(hi));
  return r;
}

DEV void gload_lds16(const void* g, void* l) {
  __builtin_amdgcn_global_load_lds(
      (const __attribute__((address_space(1))) void*)g,
      (__attribute__((address_space(3))) void*)l, 16, 0, 0);
}

// ---------------- fused fp32 -> bf16 convert (3 buffers, 1 launch) ---------
__global__ void __launch_bounds__(256) f2bf3_kernel(
    const float* __restrict__ a, ushort_t* __restrict__ oa, int na4,
    const float* __restrict__ b, ushort_t* __restrict__ ob, int nb4,
    const float* __restrict__ c, ushort_t* __restrict__ oc, int nc4) {
  int stride = gridDim.x * blockDim.x;
  int ntot = na4 + nb4 + nc4;
  for (int i = blockIdx.x * blockDim.x + threadIdx.x; i < ntot; i += stride) {
    const float* src;
    ushort_t* dst;
    int j = i;
    if (j < na4) {
      src = a; dst = oa;
    } else if (j < na4 + nb4) {
      j -= na4; src = b; dst = ob;
    } else {
      j -= na4 + nb4; src = c; dst = oc;
    }
    float4 v = reinterpret_cast<const float4*>(src)[j];
    ushort4 o;
    o.x = f2bf(v.x); o.y = f2bf(v.y); o.z = f2bf(v.z); o.w = f2bf(v.w);
    reinterpret_cast<ushort4*>(dst)[j] = o;
  }
}

// ---------------- 256x256-tile bf16 GEMM (QKV), 2-barrier, depth-1 --------
// C[m][n] = sum_k A[m][k]*Bw[n][k] + bias[n].  512 threads = 8 waves
// (2M x 4N), wave tile 128x64, acc[8][4].  LDS: 2 slots x (A 256x64 +
// B 256x64) = 128 KB.  Iter kt: stage tile kt+1 (8 gloads/thread) into
// slot nxt; vmcnt(8) retires tile kt's 8 while kt+1's stay in flight
// (never drained mid-loop); barrier; 24 ds_read_b128 -> 64 MFMA; barrier.
// Read:MFMA ratio 0.375 (vs 0.5 at 256x128), 2 barriers per K-tile.
// Chunk-XOR swizzle keeps ds_read_b128 conflict-free.
// Tiles with n0 >= 2048 write transposed into VT[b][h][d][T].
__global__ void __launch_bounds__(512) gemm256sq(
    const ushort_t* __restrict__ A, const ushort_t* __restrict__ Bw,
    const float* __restrict__ bias, ushort_t* __restrict__ Cout,
    ushort_t* __restrict__ VT, int M, int N, int K, int ldc) {
  __shared__ __align__(16) ushort_t lA[2][256 * 64];
  __shared__ __align__(16) ushort_t lB[2][256 * 64];
  const int tid = threadIdx.x;
  const int lane = tid & 63;
  const int wid = tid >> 6;
  const int wm = wid >> 2;   // 0..1  (M half, 128 rows)
  const int wn = wid & 3;    // 0..3  (64-col band)
  const int r0 = lane & 15;
  const int p = lane >> 4;
  const int rg = p * 4;

  // XCD-aware bijective chunk swizzle
  const int nbn = N >> 8;                  // 12 (QKV)
  const int G = (M >> 8) * nbn;            // 384, %8==0
  const int lin = blockIdx.x;
  const int cpx = G >> 3;
  const int swz = (lin & 7) * cpx + (lin >> 3);
  const int m0 = (swz / nbn) << 8;
  const int n0 = (swz % nbn) << 8;

  const int NKT = K >> 6;                  // 16

  auto stage = [&](int kt, int slot) {
#pragma unroll
    for (int rnd = 0; rnd < 4; ++rnd) {
      int f = rnd * 4096 + tid * 8;
      int row = f >> 6;
      int sch = ((f >> 3) & 7) ^ (row & 7);
      gload_lds16(A + (size_t)(m0 + row) * K + kt * 64 + sch * 8,
                  &lA[slot][f]);
    }
#pragma unroll
    for (int rnd = 0; rnd < 4; ++rnd) {
      int f = rnd * 4096 + tid * 8;
      int row = f >> 6;
      int sch = ((f >> 3) & 7) ^ (row & 7);
      gload_lds16(Bw + (size_t)(n0 + row) * K + kt * 64 + sch * 8,
                  &lB[slot][f]);
    }
  };

  f32x4 acc[8][4] = {};

  // prologue: stage tile 0 into slot 0
  stage(0, 0);

  for (int kt = 0; kt < NKT; ++kt) {
    const int cur = kt & 1, nxt = cur ^ 1;
    // stage tile kt+1 into slot nxt (dummy wrap at the end keeps the
    // vmcnt count uniform; dummy data is never read)
    int skt = kt + 1;
    if (skt >= NKT) skt -= NKT;
    stage(skt, nxt);

    // gate: tile kt's 8 loads are the oldest of <=16 outstanding
    asm volatile("s_waitcnt vmcnt(8)" ::: "memory");
    __builtin_amdgcn_sched_barrier(0);
    asm volatile("s_barrier" ::: "memory");
    __builtin_amdgcn_sched_barrier(0);

    const ushort_t* bA = &lA[cur][0];
    const ushort_t* bB = &lB[cur][0];

#pragma unroll
    for (int kc = 0; kc < 2; ++kc) {
      const int ch = (kc * 4 + p) ^ (r0 & 7);
      short8 aF[8], bF[4];
#pragma unroll
      for (int mi = 0; mi < 8; ++mi) {
        int row = wm * 128 + mi * 16 + r0;
        aF[mi] = *(const short8*)&bA[row * 64 + ch * 8];
      }
#pragma unroll
      for (int ni = 0; ni < 4; ++ni) {
        int row = wn * 64 + ni * 16 + r0;
        bF[ni] = *(const short8*)&bB[row * 64 + ch * 8];
      }
      __builtin_amdgcn_s_setprio(1);
#pragma unroll
      for (int mi = 0; mi < 8; ++mi)
#pragma unroll
        for (int ni = 0; ni < 4; ++ni)
          acc[mi][ni] = __builtin_amdgcn_mfma_f32_16x16x32_bf16(
              aF[mi], bF[ni], acc[mi][ni], 0, 0, 0);
      __builtin_amdgcn_s_setprio(0);
    }

    asm volatile("s_barrier" ::: "memory");  // reads of slot cur done (WAR)
    __builtin_amdgcn_sched_barrier(0);
  }

  // epilogue
#pragma unroll
  for (int mi = 0; mi < 8; ++mi) {
    int m = m0 + wm * 128 + mi * 16 + rg;
#pragma unroll
    for (int ni = 0; ni < 4; ++ni) {
      int n = n0 + wn * 64 + ni * 16 + r0;
      float bv = bias[n];
      if (n >= 2048) {  // V path: write transposed into VT[b][h][d][T]
        int vcol = n - 2048;
        int hh = vcol >> 6, dd = vcol & 63;
        int bb = m >> 11, tt = m & 2047;
        ushort4 o;
        o.x = f2bf(acc[mi][ni][0] + bv);
        o.y = f2bf(acc[mi][ni][1] + bv);
        o.z = f2bf(acc[mi][ni][2] + bv);
        o.w = f2bf(acc[mi][ni][3] + bv);
        *reinterpret_cast<ushort4*>(
            &VT[((size_t)((bb << 4) + hh) * 64 + dd) * (size_t)T_ + tt]) = o;
      } else {
#pragma unroll
        for (int r = 0; r < 4; ++r)
          Cout[(size_t)(m + r) * ldc + n] = f2bf(acc[mi][ni][r] + bv);
      }
    }
  }
}

// ---------------- bf16 GEMM (proj), 256x128 tile, depth-2 prefetch --------
template <bool OUT_BF16>
__global__ void __launch_bounds__(512) gemm256(
    const ushort_t* __restrict__ A, const ushort_t* __restrict__ Bw,
    const float* __restrict__ bias, void* __restrict__ Cout,
    int M, int N, int K, int ldc) {
  __shared__ __align__(16) ushort_t lA[3][256 * 64];
  __shared__ __align__(16) ushort_t lB[3][128 * 64];
  const int tid = threadIdx.x;
  const int lane = tid & 63;
  const int wid = tid >> 6;
  const int wm = wid >> 1, wn = wid & 1;
  const int r0 = lane & 15;
  const int p = lane >> 4;
  const int rg = p * 4;

  const int nbn = N >> 7;
  const int G = (M >> 8) * nbn;
  const int lin = blockIdx.x;
  const int cpx = G >> 3;
  const int swz = (lin & 7) * cpx + (lin >> 3);
  const int m0 = (swz / nbn) << 8;
  const int n0 = (swz % nbn) << 7;

  const int NKT = K >> 6;

  auto stage = [&](int kt, int slot) {
#pragma unroll
    for (int rnd = 0; rnd < 4; ++rnd) {
      int f = rnd * 4096 + tid * 8;
      int row = f >> 6;
      int sch = ((f >> 3) & 7) ^ (row & 7);
      gload_lds16(A + (size_t)(m0 + row) * K + kt * 64 + sch * 8,
                  &lA[slot][f]);
    }
#pragma unroll
    for (int rnd = 0; rnd < 2; ++rnd) {
      int f = rnd * 4096 + tid * 8;
      int row = f >> 6;
      int sch = ((f >> 3) & 7) ^ (row & 7);
      gload_lds16(Bw + (size_t)(n0 + row) * K + kt * 64 + sch * 8,
                  &lB[slot][f]);
    }
  };

  f32x4 acc[4][4] = {};

  stage(0, 0);
  stage(1, 1);

  for (int kt = 0; kt < NKT; ++kt) {
    int skt = kt + 2;
    if (skt >= NKT) skt -= NKT;
    stage(skt, (kt + 2) % 3);

    asm volatile("s_waitcnt vmcnt(12)" ::: "memory");
    __builtin_amdgcn_sched_barrier(0);
    asm volatile("s_barrier" ::: "memory");
    __builtin_amdgcn_sched_barrier(0);

    const ushort_t* bA = &lA[kt % 3][0];
    const ushort_t* bB = &lB[kt % 3][0];

    short8 aF[2][4], bF[2][4];
#pragma unroll
    for (int kc = 0; kc < 2; ++kc)
#pragma unroll
      for (int mi = 0; mi < 4; ++mi) {
        int row = wm * 64 + mi * 16 + r0;
        int ch = (kc * 4 + p) ^ (row & 7);
        aF[kc][mi] = *(const short8*)&bA[row * 64 + ch * 8];
      }
#pragma unroll
    for (int kc = 0; kc < 2; ++kc)
#pragma unroll
      for (int ni = 0; ni < 4; ++ni) {
        int row = wn * 64 + ni * 16 + r0;
        int ch = (kc * 4 + p) ^ (row & 7);
        bF[kc][ni] = *(const short8*)&bB[row * 64 + ch * 8];
      }

    __builtin_amdgcn_s_setprio(1);
#pragma unroll
    for (int kc = 0; kc < 2; ++kc)
#pragma unroll
      for (int mi = 0; mi < 4; ++mi)
#pragma unroll
        for (int ni = 0; ni < 4; ++ni)
          acc[mi][ni] = __builtin_amdgcn_mfma_f32_16x16x32_bf16(
              aF[kc][mi], bF[kc][ni], acc[mi][ni], 0, 0, 0);
    __builtin_amdgcn_s_setprio(0);

    asm volatile("s_barrier" ::: "memory");
    __builtin_amdgcn_sched_barrier(0);
  }

#pragma unroll
  for (int mi = 0; mi < 4; ++mi)
#pragma unroll
    for (int ni = 0; ni < 4; ++ni) {
      int n = n0 + wn * 64 + ni * 16 + r0;
      float bv = bias[n];
#pragma unroll
      for (int r = 0; r < 4; ++r) {
        int m = m0 + wm * 64 + mi * 16 + rg + r;
        float v = acc[mi][ni][r] + bv;
        if (OUT_BF16)
          ((ushort_t*)Cout)[(size_t)m * ldc + n] = f2bf(v);
        else
          ((float*)Cout)[(size_t)m * ldc + n] = v;
      }
    }
}

// ---------------- causal flash attention ----------------
// Merged-pair sweep, fixed-shift softmax, 2-phase dbuf staging, XCD-aware
// bh remap.  NEW: K fragments are read from LDS ONCE per kv-tile and feed
// both q-tiles' QK^T MFMAs (saves 8 ds_read_b128 on dual-active iters).
__global__ void __launch_bounds__(256, 4) attn_kernel(
    const ushort_t* __restrict__ qk, const ushort_t* __restrict__ Vt,
    ushort_t* __restrict__ O) {
  __shared__ __align__(16) ushort_t lK[2][64 * 64];
  __shared__ __align__(16) ushort_t lVT[2][64 * 64];
  __shared__ __align__(16) ushort_t lP[4][16 * 64];

  const int tid = threadIdx.x;
  const int lane = tid & 63;
  const int w = tid >> 6;
  const int r0 = lane & 15;
  const int p = lane >> 4;
  const int g8 = p * 8;
  const int rg = p * 4;

  const int lin = (int)blockIdx.y * 16 + (int)blockIdx.x;
  const int xcd = lin & 7;
  const int chunk = lin >> 3;
  const int bh = xcd * 8 + (chunk >> 4);
  const int pair = chunk & 15;

  const int b = bh >> 4, h = bh & 15;
  const float QSC = 0.125f * LOG2E_;

  const short8 bOne = {0x3F80, 0x3F80, 0x3F80, 0x3F80,
                       0x3F80, 0x3F80, 0x3F80, 0x3F80};

  ushort_t* lPw = &lP[w][0];

  const int f0 = tid * 8;
  const int row0 = f0 >> 6;
  const int lch0 = ((f0 >> 3) & 7) ^ (row0 & 7);
  const int f1 = 2048 + tid * 8;
  const int row1 = f1 >> 6;
  const int lch1 = ((f1 >> 3) & 7) ^ (row1 & 7);

  const int qb1 = pair;
  const int qb2 = 31 - pair;
  const int q1 = qb1 * 64 + w * 16;
  const int q2 = qb2 * 64 + w * 16;

  short8 aQ1[2], aQ2[2];
#pragma unroll
  for (int kc = 0; kc < 2; ++kc) {
    short8 raw1 = *(const short8*)(qk + (size_t)(b * T_ + q1 + r0) * 2048 +
                                   h * 64 + kc * 32 + g8);
    short8 raw2 = *(const short8*)(qk + (size_t)(b * T_ + q2 + r0) * 2048 +
                                   h * 64 + kc * 32 + g8);
    short8 s1, s2;
#pragma unroll
    for (int j = 0; j < 4; ++j) {
      unsigned pk1 = cvt_pk_bf16(bf2f((ushort_t)raw1[2 * j]) * QSC,
                                 bf2f((ushort_t)raw1[2 * j + 1]) * QSC);
      unsigned pk2 = cvt_pk_bf16(bf2f((ushort_t)raw2[2 * j]) * QSC,
                                 bf2f((ushort_t)raw2[2 * j + 1]) * QSC);
      s1[2 * j] = (short)(ushort_t)pk1;
      s1[2 * j + 1] = (short)(ushort_t)(pk1 >> 16);
      s2[2 * j] = (short)(ushort_t)pk2;
      s2[2 * j + 1] = (short)(ushort_t)(pk2 >> 16);
    }
    aQ1[kc] = s1;
    aQ2[kc] = s2;
  }

  f32x4 accO1[4] = {}, accO2[4] = {};
  f32x4 accL1 = {}, accL2 = {};

  {
    const ushort_t* kb = qk + (size_t)(b * T_) * 2048 + 1024 + h * 64;
    const ushort_t* vb = Vt + (size_t)bh * 64 * (size_t)T_;
    gload_lds16(kb + (size_t)row0 * 2048 + lch0 * 8, &lK[0][f0]);
    gload_lds16(kb + (size_t)row1 * 2048 + lch1 * 8, &lK[0][f1]);
    gload_lds16(vb + (size_t)row0 * T_ + lch0 * 8, &lVT[0][f0]);
    gload_lds16(vb + (size_t)row1 * T_ + lch1 * 8, &lVT[0][f1]);
  }
  int cur = 0;

  auto procPV = [&](f32x4* sA, const ushort_t* bufV, f32x4* accO,
                    f32x4& accL) {
#pragma unroll
    for (int ni = 0; ni < 4; ++ni) {
      float p0 = exp2f(sA[ni][0]);
      float p1 = exp2f(sA[ni][1]);
      float p2 = exp2f(sA[ni][2]);
      float p3 = exp2f(sA[ni][3]);
      unsigned lo = cvt_pk_bf16(p0, p1);
      unsigned hi = cvt_pk_bf16(p2, p3);
      int col = ni * 16 + r0;
#pragma unroll
      for (int r = 0; r < 4; ++r) {
        int rowp = rg + r;
        ushort_t hw = (r == 0)   ? (ushort_t)lo
                      : (r == 1) ? (ushort_t)(lo >> 16)
                      : (r == 2) ? (ushort_t)hi
                                 : (ushort_t)(hi >> 16);
        lPw[rowp * 64 + (col ^ ((rowp & 7) << 3))] = hw;
      }
    }
    __builtin_amdgcn_s_setprio(1);
#pragma unroll
    for (int kc = 0; kc < 2; ++kc) {
      int pch = (kc * 4 + p) ^ (r0 & 7);
      short8 aP = *(const short8*)&lPw[r0 * 64 + pch * 8];
      accL = __builtin_amdgcn_mfma_f32_16x16x32_bf16(aP, bOne, accL, 0, 0, 0);
#pragma unroll
      for (int ni = 0; ni < 4; ++ni) {
        int row = ni * 16 + r0;
        int ch = (kc * 4 + p) ^ (row & 7);
        short8 bV = *(const short8*)&bufV[row * 64 + ch * 8];
        accO[ni] =
            __builtin_amdgcn_mfma_f32_16x16x32_bf16(aP, bV, accO[ni], 0, 0, 0);
      }
    }
    __builtin_amdgcn_s_setprio(0);
  };

  for (int kt = 0; kt <= qb2; ++kt) {
    __syncthreads();

    if (kt < qb2) {
      const ushort_t* kb =
          qk + (size_t)(b * T_ + (kt + 1) * 64) * 2048 + 1024 + h * 64;
      const ushort_t* vb = Vt + (size_t)bh * 64 * (size_t)T_ + (kt + 1) * 64;
      ushort_t* dK = &lK[cur ^ 1][0];
      ushort_t* dV = &lVT[cur ^ 1][0];
      gload_lds16(kb + (size_t)row0 * 2048 + lch0 * 8, dK + f0);
      gload_lds16(kb + (size_t)row1 * 2048 + lch1 * 8, dK + f1);
      gload_lds16(vb + (size_t)row0 * T_ + lch0 * 8, dV + f0);
      gload_lds16(vb + (size_t)row1 * T_ + lch1 * 8, dV + f1);
    }

    const ushort_t* bufK = &lK[cur][0];
    const ushort_t* bufV = &lVT[cur][0];
    const bool act1 = (kt <= qb1);

    // ---- QK^T for BOTH tiles, K fragments read once ----
    f32x4 sA1[4], sA2[4];
#pragma unroll
    for (int ni = 0; ni < 4; ++ni) {
      sA1[ni] = f32x4{-16.f, -16.f, -16.f, -16.f};
      sA2[ni] = f32x4{-16.f, -16.f, -16.f, -16.f};
    }
    __builtin_amdgcn_s_setprio(1);
#pragma unroll
    for (int kc = 0; kc < 2; ++kc)
#pragma unroll
      for (int ni = 0; ni < 4; ++ni) {
        int row = ni * 16 + r0;
        int ch = (kc * 4 + p) ^ (row & 7);
        short8 bK = *(const short8*)&bufK[row * 64 + ch * 8];
        sA2[ni] =
            __builtin_amdgcn_mfma_f32_16x16x32_bf16(aQ2[kc], bK, sA2[ni], 0, 0, 0);
        if (act1)
          sA1[ni] = __builtin_amdgcn_mfma_f32_16x16x32_bf16(aQ1[kc], bK,
                                                            sA1[ni], 0, 0, 0);
      }
    __builtin_amdgcn_s_setprio(0);

    if (kt == qb2) {  // tile-2 diagonal (last iteration)
#pragma unroll
      for (int ni = 0; ni < 4; ++ni) {
        if (ni > w) {
#pragma unroll
          for (int r = 0; r < 4; ++r) sA2[ni][r] = -1e30f;
        } else if (ni == w) {
#pragma unroll
          for (int r = 0; r < 4; ++r)
            if (r0 > rg + r) sA2[ni][r] = -1e30f;
        }
      }
    }
    procPV(sA2, bufV, accO2, accL2);

    if (act1) {
      if (kt == qb1) {  // tile-1 diagonal
#pragma unroll
        for (int ni = 0; ni < 4; ++ni) {
          if (ni > w) {
#pragma unroll
            for (int r = 0; r < 4; ++r) sA1[ni][r] = -1e30f;
          } else if (ni == w) {
#pragma unroll
            for (int r = 0; r < 4; ++r)
              if (r0 > rg + r) sA1[ni][r] = -1e30f;
          }
        }
      }
      procPV(sA1, bufV, accO1, accL1);
    }

    cur ^= 1;
  }

#pragma unroll
  for (int ni = 0; ni < 4; ++ni)
#pragma unroll
    for (int r = 0; r < 4; ++r) {
      int d = h * 64 + ni * 16 + r0;
      float v1 = accO1[ni][r] / accL1[r];
      float v2 = accO2[ni][r] / accL2[r];
      O[(size_t)(b * T_ + q1 + rg + r) * 1024 + d] = f2bf(v1);
      O[(size_t)(b * T_ + q2 + rg + r) * 1024 + d] = f2bf(v2);
    }
}

extern "C" void kernel_launch(void* const* d_in, const int* in_sizes, int n_in,
                              void* d_out, int out_size, void* d_ws, size_t ws_size,
                              hipStream_t stream) {
  const float* x = (const float*)d_in[0];
  const float* Wqkv = (const float*)d_in[1];
  const float* bqkv = (const float*)d_in[2];
  const float* Wproj = (const float*)d_in[3];
  const float* bproj = (const float*)d_in[4];
  float* out = (float*)d_out;

  ushort_t* xb = (ushort_t*)d_ws;                       // [8192][1024]
  ushort_t* wqkvb = xb + (size_t)M_ * D_;               // [3072][1024]
  ushort_t* wprojb = wqkvb + (size_t)3 * D_ * D_;       // [1024][1024]
  ushort_t* qkb = wprojb + (size_t)D_ * D_;             // [8192][2048] (Q|K)
  ushort_t* Vt = qkb + (size_t)M_ * 2048;               // [64][64][2048]
  ushort_t* Ob = Vt + (size_t)M_ * D_;                  // [8192][1024]

  f2bf3_kernel<<<2048, 256, 0, stream>>>(
      x, xb, M_ * D_ / 4,
      Wqkv, wqkvb, 3 * D_ * D_ / 4,
      Wproj, wprojb, D_ * D_ / 4);

  // QKV: (8192/256) * (3072/256) = 32*12 = 384 blocks, 256x256 2-barrier
  gemm256sq<<<384, 512, 0, stream>>>(
      xb, wqkvb, bqkv, qkb, Vt, M_, 3 * D_, D_, 2048);

  attn_kernel<<<dim3(16, 64), 256, 0, stream>>>(qkb, Vt, Ob);

  // proj: (8192/256) * (1024/128) = 32*8 = 256 blocks (1 exact CU round)
  gemm256<false><<<256, 512, 0, stream>>>(
      Ob, wprojb, bproj, out, M_, D_, D_, D_);
}

// Round 15
// 187.893 us; speedup vs baseline: 2.2072x; 2.2072x over previous
//
#include <hip/hip_runtime.h>

typedef unsigned short ushort_t;
typedef __attribute__((ext_vector_type(8))) short short8;
typedef __attribute__((ext_vector_type(4))) float f32x4;

#define DEV __device__ __forceinline__

constexpr int B_ = 4, T_ = 2048, D_ = 1024, H_ = 16;
constexpr int M_ = B_ * T_;                 // 8192 rows
constexpr float LOG2E_ = 1.4426950408889634f;

DEV ushort_t f2bf(float f) {
  union { float f; unsigned u; } c; c.f = f;
  unsigned u = c.u;
  return (ushort_t)((u + 0x7fffu + ((u >> 16) & 1u)) >> 16);
}
DEV float bf2f(ushort_t b) {
  union { unsigned u; float f; } c; c.u = ((unsigned)b) << 16;
  return c.f;
}
DEV unsigned cvt_pk_bf16(float lo, float hi) {
  unsigned r;
  asm("v_cvt_pk_bf16_f32 %0, %1, %2" : "=v"(r) : "v"(lo), "v"(hi));
  return r;
}

DEV void gload_lds16(const void* g, void* l) {
  __builtin_amdgcn_global_load_lds(
      (const __attribute__((address_space(1))) void*)g,
      (__attribute__((address_space(3))) void*)l, 16, 0, 0);
}

// ---------------- fused fp32 -> bf16 convert (3 buffers, 1 launch) ---------
__global__ void __launch_bounds__(256) f2bf3_kernel(
    const float* __restrict__ a, ushort_t* __restrict__ oa, int na4,
    const float* __restrict__ b, ushort_t* __restrict__ ob, int nb4,
    const float* __restrict__ c, ushort_t* __restrict__ oc, int nc4) {
  int stride = gridDim.x * blockDim.x;
  int ntot = na4 + nb4 + nc4;
  for (int i = blockIdx.x * blockDim.x + threadIdx.x; i < ntot; i += stride) {
    const float* src;
    ushort_t* dst;
    int j = i;
    if (j < na4) {
      src = a; dst = oa;
    } else if (j < na4 + nb4) {
      j -= na4; src = b; dst = ob;
    } else {
      j -= na4 + nb4; src = c; dst = oc;
    }
    float4 v = reinterpret_cast<const float4*>(src)[j];
    ushort4 o;
    o.x = f2bf(v.x); o.y = f2bf(v.y); o.z = f2bf(v.z); o.w = f2bf(v.w);
    reinterpret_cast<ushort4*>(dst)[j] = o;
  }
}

// ---------------- 256x256-tile bf16 GEMM (QKV), 2-barrier, depth-1 --------
// 512 threads = 8 waves (2M x 4N), wave tile 128x64, acc[8][4].
// LDS: 2 slots x (A 256x64 + B 256x64) = 128 KB.  Iter kt: stage tile kt+1
// into slot nxt; vmcnt(8) retires tile kt while kt+1 stays in flight;
// barrier; 24 ds_read_b128 -> 64 MFMA; barrier.  Chunk-XOR swizzle.
// Tiles with n0 >= 2048 write transposed into VT[b][h][d][T].
__global__ void __launch_bounds__(512) gemm256sq(
    const ushort_t* __restrict__ A, const ushort_t* __restrict__ Bw,
    const float* __restrict__ bias, ushort_t* __restrict__ Cout,
    ushort_t* __restrict__ VT, int M, int N, int K, int ldc) {
  __shared__ __align__(16) ushort_t lA[2][256 * 64];
  __shared__ __align__(16) ushort_t lB[2][256 * 64];
  const int tid = threadIdx.x;
  const int lane = tid & 63;
  const int wid = tid >> 6;
  const int wm = wid >> 2;   // 0..1  (M half, 128 rows)
  const int wn = wid & 3;    // 0..3  (64-col band)
  const int r0 = lane & 15;
  const int p = lane >> 4;
  const int rg = p * 4;

  // XCD-aware bijective chunk swizzle
  const int nbn = N >> 8;                  // 12 (QKV)
  const int G = (M >> 8) * nbn;            // 384, %8==0
  const int lin = blockIdx.x;
  const int cpx = G >> 3;
  const int swz = (lin & 7) * cpx + (lin >> 3);
  const int m0 = (swz / nbn) << 8;
  const int n0 = (swz % nbn) << 8;

  const int NKT = K >> 6;                  // 16

  auto stage = [&](int kt, int slot) {
#pragma unroll
    for (int rnd = 0; rnd < 4; ++rnd) {
      int f = rnd * 4096 + tid * 8;
      int row = f >> 6;
      int sch = ((f >> 3) & 7) ^ (row & 7);
      gload_lds16(A + (size_t)(m0 + row) * K + kt * 64 + sch * 8,
                  &lA[slot][f]);
    }
#pragma unroll
    for (int rnd = 0; rnd < 4; ++rnd) {
      int f = rnd * 4096 + tid * 8;
      int row = f >> 6;
      int sch = ((f >> 3) & 7) ^ (row & 7);
      gload_lds16(Bw + (size_t)(n0 + row) * K + kt * 64 + sch * 8,
                  &lB[slot][f]);
    }
  };

  f32x4 acc[8][4] = {};

  // prologue: stage tile 0 into slot 0
  stage(0, 0);

  for (int kt = 0; kt < NKT; ++kt) {
    const int cur = kt & 1, nxt = cur ^ 1;
    int skt = kt + 1;
    if (skt >= NKT) skt -= NKT;
    stage(skt, nxt);

    asm volatile("s_waitcnt vmcnt(8)" ::: "memory");
    __builtin_amdgcn_sched_barrier(0);
    asm volatile("s_barrier" ::: "memory");
    __builtin_amdgcn_sched_barrier(0);

    const ushort_t* bA = &lA[cur][0];
    const ushort_t* bB = &lB[cur][0];

#pragma unroll
    for (int kc = 0; kc < 2; ++kc) {
      const int ch = (kc * 4 + p) ^ (r0 & 7);
      short8 aF[8], bF[4];
#pragma unroll
      for (int mi = 0; mi < 8; ++mi) {
        int row = wm * 128 + mi * 16 + r0;
        aF[mi] = *(const short8*)&bA[row * 64 + ch * 8];
      }
#pragma unroll
      for (int ni = 0; ni < 4; ++ni) {
        int row = wn * 64 + ni * 16 + r0;
        bF[ni] = *(const short8*)&bB[row * 64 + ch * 8];
      }
      __builtin_amdgcn_s_setprio(1);
#pragma unroll
      for (int mi = 0; mi < 8; ++mi)
#pragma unroll
        for (int ni = 0; ni < 4; ++ni)
          acc[mi][ni] = __builtin_amdgcn_mfma_f32_16x16x32_bf16(
              aF[mi], bF[ni], acc[mi][ni], 0, 0, 0);
      __builtin_amdgcn_s_setprio(0);
    }

    asm volatile("s_barrier" ::: "memory");  // reads of slot cur done (WAR)
    __builtin_amdgcn_sched_barrier(0);
  }

  // epilogue
#pragma unroll
  for (int mi = 0; mi < 8; ++mi) {
    int m = m0 + wm * 128 + mi * 16 + rg;
#pragma unroll
    for (int ni = 0; ni < 4; ++ni) {
      int n = n0 + wn * 64 + ni * 16 + r0;
      float bv = bias[n];
      if (n >= 2048) {  // V path: write transposed into VT[b][h][d][T]
        int vcol = n - 2048;
        int hh = vcol >> 6, dd = vcol & 63;
        int bb = m >> 11, tt = m & 2047;
        ushort4 o;
        o.x = f2bf(acc[mi][ni][0] + bv);
        o.y = f2bf(acc[mi][ni][1] + bv);
        o.z = f2bf(acc[mi][ni][2] + bv);
        o.w = f2bf(acc[mi][ni][3] + bv);
        *reinterpret_cast<ushort4*>(
            &VT[((size_t)((bb << 4) + hh) * 64 + dd) * (size_t)T_ + tt]) = o;
      } else {
#pragma unroll
        for (int r = 0; r < 4; ++r)
          Cout[(size_t)(m + r) * ldc + n] = f2bf(acc[mi][ni][r] + bv);
      }
    }
  }
}

// ---------------- bf16 GEMM (proj), 256x128 tile, depth-2 prefetch --------
template <bool OUT_BF16>
__global__ void __launch_bounds__(512) gemm256(
    const ushort_t* __restrict__ A, const ushort_t* __restrict__ Bw,
    const float* __restrict__ bias, void* __restrict__ Cout,
    int M, int N, int K, int ldc) {
  __shared__ __align__(16) ushort_t lA[3][256 * 64];
  __shared__ __align__(16) ushort_t lB[3][128 * 64];
  const int tid = threadIdx.x;
  const int lane = tid & 63;
  const int wid = tid >> 6;
  const int wm = wid >> 1, wn = wid & 1;
  const int r0 = lane & 15;
  const int p = lane >> 4;
  const int rg = p * 4;

  const int nbn = N >> 7;
  const int G = (M >> 8) * nbn;
  const int lin = blockIdx.x;
  const int cpx = G >> 3;
  const int swz = (lin & 7) * cpx + (lin >> 3);
  const int m0 = (swz / nbn) << 8;
  const int n0 = (swz % nbn) << 7;

  const int NKT = K >> 6;

  auto stage = [&](int kt, int slot) {
#pragma unroll
    for (int rnd = 0; rnd < 4; ++rnd) {
      int f = rnd * 4096 + tid * 8;
      int row = f >> 6;
      int sch = ((f >> 3) & 7) ^ (row & 7);
      gload_lds16(A + (size_t)(m0 + row) * K + kt * 64 + sch * 8,
                  &lA[slot][f]);
    }
#pragma unroll
    for (int rnd = 0; rnd < 2; ++rnd) {
      int f = rnd * 4096 + tid * 8;
      int row = f >> 6;
      int sch = ((f >> 3) & 7) ^ (row & 7);
      gload_lds16(Bw + (size_t)(n0 + row) * K + kt * 64 + sch * 8,
                  &lB[slot][f]);
    }
  };

  f32x4 acc[4][4] = {};

  stage(0, 0);
  stage(1, 1);

  for (int kt = 0; kt < NKT; ++kt) {
    int skt = kt + 2;
    if (skt >= NKT) skt -= NKT;
    stage(skt, (kt + 2) % 3);

    asm volatile("s_waitcnt vmcnt(12)" ::: "memory");
    __builtin_amdgcn_sched_barrier(0);
    asm volatile("s_barrier" ::: "memory");
    __builtin_amdgcn_sched_barrier(0);

    const ushort_t* bA = &lA[kt % 3][0];
    const ushort_t* bB = &lB[kt % 3][0];

    short8 aF[2][4], bF[2][4];
#pragma unroll
    for (int kc = 0; kc < 2; ++kc)
#pragma unroll
      for (int mi = 0; mi < 4; ++mi) {
        int row = wm * 64 + mi * 16 + r0;
        int ch = (kc * 4 + p) ^ (row & 7);
        aF[kc][mi] = *(const short8*)&bA[row * 64 + ch * 8];
      }
#pragma unroll
    for (int kc = 0; kc < 2; ++kc)
#pragma unroll
      for (int ni = 0; ni < 4; ++ni) {
        int row = wn * 64 + ni * 16 + r0;
        int ch = (kc * 4 + p) ^ (row & 7);
        bF[kc][ni] = *(const short8*)&bB[row * 64 + ch * 8];
      }

    __builtin_amdgcn_s_setprio(1);
#pragma unroll
    for (int kc = 0; kc < 2; ++kc)
#pragma unroll
      for (int mi = 0; mi < 4; ++mi)
#pragma unroll
        for (int ni = 0; ni < 4; ++ni)
          acc[mi][ni] = __builtin_amdgcn_mfma_f32_16x16x32_bf16(
              aF[kc][mi], bF[kc][ni], acc[mi][ni], 0, 0, 0);
    __builtin_amdgcn_s_setprio(0);

    asm volatile("s_barrier" ::: "memory");
    __builtin_amdgcn_sched_barrier(0);
  }

#pragma unroll
  for (int mi = 0; mi < 4; ++mi)
#pragma unroll
    for (int ni = 0; ni < 4; ++ni) {
      int n = n0 + wn * 64 + ni * 16 + r0;
      float bv = bias[n];
#pragma unroll
      for (int r = 0; r < 4; ++r) {
        int m = m0 + wm * 64 + mi * 16 + rg + r;
        float v = acc[mi][ni][r] + bv;
        if (OUT_BF16)
          ((ushort_t*)Cout)[(size_t)m * ldc + n] = f2bf(v);
        else
          ((float*)Cout)[(size_t)m * ldc + n] = v;
      }
    }
}

// ---------------- causal flash attention (R13 version, reverted) ----------
// Merged-pair sweep, fixed-shift softmax, 2-phase dbuf staging, XCD-aware
// bh remap.  Tiles processed SEQUENTIALLY (sA2 -> procPV -> sA1 -> procPV)
// to keep live state under the 128-VGPR cap (R14's shared-K interleave
// spilled to scratch: 530 MB HBM, 3.6x slowdown).
__global__ void __launch_bounds__(256, 4) attn_kernel(
    const ushort_t* __restrict__ qk, const ushort_t* __restrict__ Vt,
    ushort_t* __restrict__ O) {
  __shared__ __align__(16) ushort_t lK[2][64 * 64];
  __shared__ __align__(16) ushort_t lVT[2][64 * 64];
  __shared__ __align__(16) ushort_t lP[4][16 * 64];

  const int tid = threadIdx.x;
  const int lane = tid & 63;
  const int w = tid >> 6;
  const int r0 = lane & 15;
  const int p = lane >> 4;
  const int g8 = p * 8;
  const int rg = p * 4;

  const int lin = (int)blockIdx.y * 16 + (int)blockIdx.x;
  const int xcd = lin & 7;
  const int chunk = lin >> 3;
  const int bh = xcd * 8 + (chunk >> 4);
  const int pair = chunk & 15;

  const int b = bh >> 4, h = bh & 15;
  const float QSC = 0.125f * LOG2E_;

  const short8 bOne = {0x3F80, 0x3F80, 0x3F80, 0x3F80,
                       0x3F80, 0x3F80, 0x3F80, 0x3F80};

  ushort_t* lPw = &lP[w][0];

  const int f0 = tid * 8;
  const int row0 = f0 >> 6;
  const int lch0 = ((f0 >> 3) & 7) ^ (row0 & 7);
  const int f1 = 2048 + tid * 8;
  const int row1 = f1 >> 6;
  const int lch1 = ((f1 >> 3) & 7) ^ (row1 & 7);

  const int qb1 = pair;
  const int qb2 = 31 - pair;
  const int q1 = qb1 * 64 + w * 16;
  const int q2 = qb2 * 64 + w * 16;

  short8 aQ1[2], aQ2[2];
#pragma unroll
  for (int kc = 0; kc < 2; ++kc) {
    short8 raw1 = *(const short8*)(qk + (size_t)(b * T_ + q1 + r0) * 2048 +
                                   h * 64 + kc * 32 + g8);
    short8 raw2 = *(const short8*)(qk + (size_t)(b * T_ + q2 + r0) * 2048 +
                                   h * 64 + kc * 32 + g8);
    short8 s1, s2;
#pragma unroll
    for (int j = 0; j < 4; ++j) {
      unsigned pk1 = cvt_pk_bf16(bf2f((ushort_t)raw1[2 * j]) * QSC,
                                 bf2f((ushort_t)raw1[2 * j + 1]) * QSC);
      unsigned pk2 = cvt_pk_bf16(bf2f((ushort_t)raw2[2 * j]) * QSC,
                                 bf2f((ushort_t)raw2[2 * j + 1]) * QSC);
      s1[2 * j] = (short)(ushort_t)pk1;
      s1[2 * j + 1] = (short)(ushort_t)(pk1 >> 16);
      s2[2 * j] = (short)(ushort_t)pk2;
      s2[2 * j + 1] = (short)(ushort_t)(pk2 >> 16);
    }
    aQ1[kc] = s1;
    aQ2[kc] = s2;
  }

  f32x4 accO1[4] = {}, accO2[4] = {};
  f32x4 accL1 = {}, accL2 = {};

  {
    const ushort_t* kb = qk + (size_t)(b * T_) * 2048 + 1024 + h * 64;
    const ushort_t* vb = Vt + (size_t)bh * 64 * (size_t)T_;
    gload_lds16(kb + (size_t)row0 * 2048 + lch0 * 8, &lK[0][f0]);
    gload_lds16(kb + (size_t)row1 * 2048 + lch1 * 8, &lK[0][f1]);
    gload_lds16(vb + (size_t)row0 * T_ + lch0 * 8, &lVT[0][f0]);
    gload_lds16(vb + (size_t)row1 * T_ + lch1 * 8, &lVT[0][f1]);
  }
  int cur = 0;

  auto procPV = [&](f32x4* sA, const ushort_t* bufV, f32x4* accO,
                    f32x4& accL) {
#pragma unroll
    for (int ni = 0; ni < 4; ++ni) {
      float p0 = exp2f(sA[ni][0]);
      float p1 = exp2f(sA[ni][1]);
      float p2 = exp2f(sA[ni][2]);
      float p3 = exp2f(sA[ni][3]);
      unsigned lo = cvt_pk_bf16(p0, p1);
      unsigned hi = cvt_pk_bf16(p2, p3);
      int col = ni * 16 + r0;
#pragma unroll
      for (int r = 0; r < 4; ++r) {
        int rowp = rg + r;
        ushort_t hw = (r == 0)   ? (ushort_t)lo
                      : (r == 1) ? (ushort_t)(lo >> 16)
                      : (r == 2) ? (ushort_t)hi
                                 : (ushort_t)(hi >> 16);
        lPw[rowp * 64 + (col ^ ((rowp & 7) << 3))] = hw;
      }
    }
    __builtin_amdgcn_s_setprio(1);
#pragma unroll
    for (int kc = 0; kc < 2; ++kc) {
      int pch = (kc * 4 + p) ^ (r0 & 7);
      short8 aP = *(const short8*)&lPw[r0 * 64 + pch * 8];
      accL = __builtin_amdgcn_mfma_f32_16x16x32_bf16(aP, bOne, accL, 0, 0, 0);
#pragma unroll
      for (int ni = 0; ni < 4; ++ni) {
        int row = ni * 16 + r0;
        int ch = (kc * 4 + p) ^ (row & 7);
        short8 bV = *(const short8*)&bufV[row * 64 + ch * 8];
        accO[ni] =
            __builtin_amdgcn_mfma_f32_16x16x32_bf16(aP, bV, accO[ni], 0, 0, 0);
      }
    }
    __builtin_amdgcn_s_setprio(0);
  };

  for (int kt = 0; kt <= qb2; ++kt) {
    __syncthreads();

    if (kt < qb2) {
      const ushort_t* kb =
          qk + (size_t)(b * T_ + (kt + 1) * 64) * 2048 + 1024 + h * 64;
      const ushort_t* vb = Vt + (size_t)bh * 64 * (size_t)T_ + (kt + 1) * 64;
      ushort_t* dK = &lK[cur ^ 1][0];
      ushort_t* dV = &lVT[cur ^ 1][0];
      gload_lds16(kb + (size_t)row0 * 2048 + lch0 * 8, dK + f0);
      gload_lds16(kb + (size_t)row1 * 2048 + lch1 * 8, dK + f1);
      gload_lds16(vb + (size_t)row0 * T_ + lch0 * 8, dV + f0);
      gload_lds16(vb + (size_t)row1 * T_ + lch1 * 8, dV + f1);
    }

    const ushort_t* bufK = &lK[cur][0];
    const ushort_t* bufV = &lVT[cur][0];
    const bool act1 = (kt <= qb1);

    f32x4 sA2[4];
#pragma unroll
    for (int ni = 0; ni < 4; ++ni)
      sA2[ni] = f32x4{-16.f, -16.f, -16.f, -16.f};
    __builtin_amdgcn_s_setprio(1);
#pragma unroll
    for (int kc = 0; kc < 2; ++kc)
#pragma unroll
      for (int ni = 0; ni < 4; ++ni) {
        int row = ni * 16 + r0;
        int ch = (kc * 4 + p) ^ (row & 7);
        short8 bK = *(const short8*)&bufK[row * 64 + ch * 8];
        sA2[ni] =
            __builtin_amdgcn_mfma_f32_16x16x32_bf16(aQ2[kc], bK, sA2[ni], 0, 0, 0);
      }
    __builtin_amdgcn_s_setprio(0);
    if (kt == qb2) {
#pragma unroll
      for (int ni = 0; ni < 4; ++ni) {
        if (ni > w) {
#pragma unroll
          for (int r = 0; r < 4; ++r) sA2[ni][r] = -1e30f;
        } else if (ni == w) {
#pragma unroll
          for (int r = 0; r < 4; ++r)
            if (r0 > rg + r) sA2[ni][r] = -1e30f;
        }
      }
    }
    procPV(sA2, bufV, accO2, accL2);

    if (act1) {
      f32x4 sA1[4];
#pragma unroll
      for (int ni = 0; ni < 4; ++ni)
        sA1[ni] = f32x4{-16.f, -16.f, -16.f, -16.f};
      __builtin_amdgcn_s_setprio(1);
#pragma unroll
      for (int kc = 0; kc < 2; ++kc)
#pragma unroll
        for (int ni = 0; ni < 4; ++ni) {
          int row = ni * 16 + r0;
          int ch = (kc * 4 + p) ^ (row & 7);
          short8 bK = *(const short8*)&bufK[row * 64 + ch * 8];
          sA1[ni] = __builtin_amdgcn_mfma_f32_16x16x32_bf16(aQ1[kc], bK,
                                                            sA1[ni], 0, 0, 0);
        }
      __builtin_amdgcn_s_setprio(0);
      if (kt == qb1) {
#pragma unroll
        for (int ni = 0; ni < 4; ++ni) {
          if (ni > w) {
#pragma unroll
            for (int r = 0; r < 4; ++r) sA1[ni][r] = -1e30f;
          } else if (ni == w) {
#pragma unroll
            for (int r = 0; r < 4; ++r)
              if (r0 > rg + r) sA1[ni][r] = -1e30f;
          }
        }
      }
      procPV(sA1, bufV, accO1, accL1);
    }

    cur ^= 1;
  }

#pragma unroll
  for (int ni = 0; ni < 4; ++ni)
#pragma unroll
    for (int r = 0; r < 4; ++r) {
      int d = h * 64 + ni * 16 + r0;
      float v1 = accO1[ni][r] / accL1[r];
      float v2 = accO2[ni][r] / accL2[r];
      O[(size_t)(b * T_ + q1 + rg + r) * 1024 + d] = f2bf(v1);
      O[(size_t)(b * T_ + q2 + rg + r) * 1024 + d] = f2bf(v2);
    }
}

extern "C" void kernel_launch(void* const* d_in, const int* in_sizes, int n_in,
                              void* d_out, int out_size, void* d_ws, size_t ws_size,
                              hipStream_t stream) {
  const float* x = (const float*)d_in[0];
  const float* Wqkv = (const float*)d_in[1];
  const float* bqkv = (const float*)d_in[2];
  const float* Wproj = (const float*)d_in[3];
  const float* bproj = (const float*)d_in[4];
  float* out = (float*)d_out;

  ushort_t* xb = (ushort_t*)d_ws;                       // [8192][1024]
  ushort_t* wqkvb = xb + (size_t)M_ * D_;               // [3072][1024]
  ushort_t* wprojb = wqkvb + (size_t)3 * D_ * D_;       // [1024][1024]
  ushort_t* qkb = wprojb + (size_t)D_ * D_;             // [8192][2048] (Q|K)
  ushort_t* Vt = qkb + (size_t)M_ * 2048;               // [64][64][2048]
  ushort_t* Ob = Vt + (size_t)M_ * D_;                  // [8192][1024]

  f2bf3_kernel<<<2048, 256, 0, stream>>>(
      x, xb, M_ * D_ / 4,
      Wqkv, wqkvb, 3 * D_ * D_ / 4,
      Wproj, wprojb, D_ * D_ / 4);

  // QKV: (8192/256) * (3072/256) = 32*12 = 384 blocks, 256x256 2-barrier
  gemm256sq<<<384, 512, 0, stream>>>(
      xb, wqkvb, bqkv, qkb, Vt, M_, 3 * D_, D_, 2048);

  attn_kernel<<<dim3(16, 64), 256, 0, stream>>>(qkb, Vt, Ob);

  // proj: (8192/256) * (1024/128) = 32*8 = 256 blocks (1 exact CU round)
  gemm256<false><<<256, 512, 0, stream>>>(
      Ob, wprojb, bproj, out, M_, D_, D_, D_);
}

// Round 16
// 183.795 us; speedup vs baseline: 2.2564x; 1.0223x over previous
//
#include <hip/hip_runtime.h>

typedef unsigned short ushort_t;
typedef __attribute__((ext_vector_type(8))) short short8;
typedef __attribute__((ext_vector_type(4))) float f32x4;

#define DEV __device__ __forceinline__

constexpr int B_ = 4, T_ = 2048, D_ = 1024, H_ = 16;
constexpr int M_ = B_ * T_;                 // 8192 rows
constexpr float LOG2E_ = 1.4426950408889634f;

DEV ushort_t f2bf(float f) {
  union { float f; unsigned u; } c; c.f = f;
  unsigned u = c.u;
  return (ushort_t)((u + 0x7fffu + ((u >> 16) & 1u)) >> 16);
}
DEV float bf2f(ushort_t b) {
  union { unsigned u; float f; } c; c.u = ((unsigned)b) << 16;
  return c.f;
}
DEV unsigned cvt_pk_bf16(float lo, float hi) {
  unsigned r;
  asm("v_cvt_pk_bf16_f32 %0, %1, %2" : "=v"(r) : "v"(lo), "v"(hi));
  return r;
}

DEV void gload_lds16(const void* g, void* l) {
  __builtin_amdgcn_global_load_lds(
      (const __attribute__((address_space(1))) void*)g,
      (__attribute__((address_space(3))) void*)l, 16, 0, 0);
}

// ---------------- fused fp32 -> bf16 convert (3 buffers, 1 launch) ---------
__global__ void __launch_bounds__(256) f2bf3_kernel(
    const float* __restrict__ a, ushort_t* __restrict__ oa, int na4,
    const float* __restrict__ b, ushort_t* __restrict__ ob, int nb4,
    const float* __restrict__ c, ushort_t* __restrict__ oc, int nc4) {
  int stride = gridDim.x * blockDim.x;
  int ntot = na4 + nb4 + nc4;
  for (int i = blockIdx.x * blockDim.x + threadIdx.x; i < ntot; i += stride) {
    const float* src;
    ushort_t* dst;
    int j = i;
    if (j < na4) {
      src = a; dst = oa;
    } else if (j < na4 + nb4) {
      j -= na4; src = b; dst = ob;
    } else {
      j -= na4 + nb4; src = c; dst = oc;
    }
    float4 v = reinterpret_cast<const float4*>(src)[j];
    ushort4 o;
    o.x = f2bf(v.x); o.y = f2bf(v.y); o.z = f2bf(v.z); o.w = f2bf(v.w);
    reinterpret_cast<ushort4*>(dst)[j] = o;
  }
}

// ---------------- bf16 GEMM, 256x128 tile, depth-2 prefetch (PROVEN) ------
// C[m][n] = sum_k A[m][k]*Bw[n][k] + bias[n].  512 threads = 8 waves
// (4M x 2N), wave tile 64x64.  LDS: 3 slots x (A 256x64 + B 128x64) =144KB.
// Iter kt stages tile kt+2 (6 gloads/thread); vmcnt(12) keeps 2 tiles in
// flight (never drained mid-loop); 2 barriers per K-step.  Chunk-XOR
// swizzle: pre-swizzled global source, linear LDS dest, XOR'd read.
// If VT != nullptr, tiles with n0 >= 2048 write transposed into VT.
template <bool OUT_BF16>
__global__ void __launch_bounds__(512) gemm256(
    const ushort_t* __restrict__ A, const ushort_t* __restrict__ Bw,
    const float* __restrict__ bias, void* __restrict__ Cout,
    ushort_t* __restrict__ VT, int M, int N, int K, int ldc) {
  __shared__ __align__(16) ushort_t lA[3][256 * 64];
  __shared__ __align__(16) ushort_t lB[3][128 * 64];
  const int tid = threadIdx.x;
  const int lane = tid & 63;
  const int wid = tid >> 6;
  const int wm = wid >> 1, wn = wid & 1;
  const int r0 = lane & 15;
  const int p = lane >> 4;
  const int rg = p * 4;

  // XCD-aware bijective chunk swizzle on the linear block index
  const int nbn = N >> 7;                  // n-blocks (24 QKV, 8 proj)
  const int G = (M >> 8) * nbn;            // total blocks (%8==0)
  const int lin = blockIdx.x;
  const int cpx = G >> 3;
  const int swz = (lin & 7) * cpx + (lin >> 3);
  const int m0 = (swz / nbn) << 8;
  const int n0 = (swz % nbn) << 7;

  const int NKT = K >> 6;                  // 16

  auto stage = [&](int kt, int slot) {
#pragma unroll
    for (int rnd = 0; rnd < 4; ++rnd) {
      int f = rnd * 4096 + tid * 8;
      int row = f >> 6;
      int sch = ((f >> 3) & 7) ^ (row & 7);
      gload_lds16(A + (size_t)(m0 + row) * K + kt * 64 + sch * 8,
                  &lA[slot][f]);
    }
#pragma unroll
    for (int rnd = 0; rnd < 2; ++rnd) {
      int f = rnd * 4096 + tid * 8;
      int row = f >> 6;
      int sch = ((f >> 3) & 7) ^ (row & 7);
      gload_lds16(Bw + (size_t)(n0 + row) * K + kt * 64 + sch * 8,
                  &lB[slot][f]);
    }
  };

  f32x4 acc[4][4] = {};

  // prologue: stage tiles 0 and 1 (12 loads in flight)
  stage(0, 0);
  stage(1, 1);

  for (int kt = 0; kt < NKT; ++kt) {
    // stage tile kt+2 (dummy wrap at the end keeps vmcnt count uniform)
    int skt = kt + 2;
    if (skt >= NKT) skt -= NKT;
    stage(skt, (kt + 2) % 3);

    // gate: tile kt's 6 loads are the oldest of <=18 outstanding
    asm volatile("s_waitcnt vmcnt(12)" ::: "memory");
    __builtin_amdgcn_sched_barrier(0);
    asm volatile("s_barrier" ::: "memory");
    __builtin_amdgcn_sched_barrier(0);

    const ushort_t* bA = &lA[kt % 3][0];
    const ushort_t* bB = &lB[kt % 3][0];

    short8 aF[2][4], bF[2][4];
#pragma unroll
    for (int kc = 0; kc < 2; ++kc)
#pragma unroll
      for (int mi = 0; mi < 4; ++mi) {
        int row = wm * 64 + mi * 16 + r0;
        int ch = (kc * 4 + p) ^ (row & 7);
        aF[kc][mi] = *(const short8*)&bA[row * 64 + ch * 8];
      }
#pragma unroll
    for (int kc = 0; kc < 2; ++kc)
#pragma unroll
      for (int ni = 0; ni < 4; ++ni) {
        int row = wn * 64 + ni * 16 + r0;
        int ch = (kc * 4 + p) ^ (row & 7);
        bF[kc][ni] = *(const short8*)&bB[row * 64 + ch * 8];
      }

    __builtin_amdgcn_s_setprio(1);
#pragma unroll
    for (int kc = 0; kc < 2; ++kc)
#pragma unroll
      for (int mi = 0; mi < 4; ++mi)
#pragma unroll
        for (int ni = 0; ni < 4; ++ni)
          acc[mi][ni] = __builtin_amdgcn_mfma_f32_16x16x32_bf16(
              aF[kc][mi], bF[kc][ni], acc[mi][ni], 0, 0, 0);
    __builtin_amdgcn_s_setprio(0);

    asm volatile("s_barrier" ::: "memory");  // reads of slot kt%3 done (WAR)
    __builtin_amdgcn_sched_barrier(0);
  }

  // epilogue
  const bool vpath = (VT != nullptr) && (n0 >= 2048);
  if (vpath) {
#pragma unroll
    for (int mi = 0; mi < 4; ++mi)
#pragma unroll
      for (int ni = 0; ni < 4; ++ni) {
        int n = n0 + wn * 64 + ni * 16 + r0;
        float bv = bias[n];
        int vcol = n - 2048;
        int hh = vcol >> 6, dd = vcol & 63;
        int m = m0 + wm * 64 + mi * 16 + rg;
        int bb = m >> 11, tt = m & 2047;
        ushort4 o;
        o.x = f2bf(acc[mi][ni][0] + bv);
        o.y = f2bf(acc[mi][ni][1] + bv);
        o.z = f2bf(acc[mi][ni][2] + bv);
        o.w = f2bf(acc[mi][ni][3] + bv);
        *reinterpret_cast<ushort4*>(
            &VT[((size_t)((bb << 4) + hh) * 64 + dd) * (size_t)T_ + tt]) = o;
      }
  } else {
#pragma unroll
    for (int mi = 0; mi < 4; ++mi)
#pragma unroll
      for (int ni = 0; ni < 4; ++ni) {
        int n = n0 + wn * 64 + ni * 16 + r0;
        float bv = bias[n];
#pragma unroll
        for (int r = 0; r < 4; ++r) {
          int m = m0 + wm * 64 + mi * 16 + rg + r;
          float v = acc[mi][ni][r] + bv;
          if (OUT_BF16)
            ((ushort_t*)Cout)[(size_t)m * ldc + n] = f2bf(v);
          else
            ((float*)Cout)[(size_t)m * ldc + n] = v;
        }
      }
  }
}

// ---------------- causal flash attention (PROVEN R13 version) -------------
// Merged-pair sweep, fixed-shift softmax (C-init -16), 2-phase dbuf
// staging, XCD-aware bh remap.  Tiles processed SEQUENTIALLY to stay
// under the 128-VGPR cap (VGPR 72; interleaving spills to scratch).
__global__ void __launch_bounds__(256, 4) attn_kernel(
    const ushort_t* __restrict__ qk, const ushort_t* __restrict__ Vt,
    ushort_t* __restrict__ O) {
  __shared__ __align__(16) ushort_t lK[2][64 * 64];
  __shared__ __align__(16) ushort_t lVT[2][64 * 64];
  __shared__ __align__(16) ushort_t lP[4][16 * 64];

  const int tid = threadIdx.x;
  const int lane = tid & 63;
  const int w = tid >> 6;
  const int r0 = lane & 15;
  const int p = lane >> 4;
  const int g8 = p * 8;
  const int rg = p * 4;

  const int lin = (int)blockIdx.y * 16 + (int)blockIdx.x;
  const int xcd = lin & 7;
  const int chunk = lin >> 3;
  const int bh = xcd * 8 + (chunk >> 4);
  const int pair = chunk & 15;

  const int b = bh >> 4, h = bh & 15;
  const float QSC = 0.125f * LOG2E_;

  const short8 bOne = {0x3F80, 0x3F80, 0x3F80, 0x3F80,
                       0x3F80, 0x3F80, 0x3F80, 0x3F80};

  ushort_t* lPw = &lP[w][0];

  const int f0 = tid * 8;
  const int row0 = f0 >> 6;
  const int lch0 = ((f0 >> 3) & 7) ^ (row0 & 7);
  const int f1 = 2048 + tid * 8;
  const int row1 = f1 >> 6;
  const int lch1 = ((f1 >> 3) & 7) ^ (row1 & 7);

  const int qb1 = pair;
  const int qb2 = 31 - pair;
  const int q1 = qb1 * 64 + w * 16;
  const int q2 = qb2 * 64 + w * 16;

  short8 aQ1[2], aQ2[2];
#pragma unroll
  for (int kc = 0; kc < 2; ++kc) {
    short8 raw1 = *(const short8*)(qk + (size_t)(b * T_ + q1 + r0) * 2048 +
                                   h * 64 + kc * 32 + g8);
    short8 raw2 = *(const short8*)(qk + (size_t)(b * T_ + q2 + r0) * 2048 +
                                   h * 64 + kc * 32 + g8);
    short8 s1, s2;
#pragma unroll
    for (int j = 0; j < 4; ++j) {
      unsigned pk1 = cvt_pk_bf16(bf2f((ushort_t)raw1[2 * j]) * QSC,
                                 bf2f((ushort_t)raw1[2 * j + 1]) * QSC);
      unsigned pk2 = cvt_pk_bf16(bf2f((ushort_t)raw2[2 * j]) * QSC,
                                 bf2f((ushort_t)raw2[2 * j + 1]) * QSC);
      s1[2 * j] = (short)(ushort_t)pk1;
      s1[2 * j + 1] = (short)(ushort_t)(pk1 >> 16);
      s2[2 * j] = (short)(ushort_t)pk2;
      s2[2 * j + 1] = (short)(ushort_t)(pk2 >> 16);
    }
    aQ1[kc] = s1;
    aQ2[kc] = s2;
  }

  f32x4 accO1[4] = {}, accO2[4] = {};
  f32x4 accL1 = {}, accL2 = {};

  {
    const ushort_t* kb = qk + (size_t)(b * T_) * 2048 + 1024 + h * 64;
    const ushort_t* vb = Vt + (size_t)bh * 64 * (size_t)T_;
    gload_lds16(kb + (size_t)row0 * 2048 + lch0 * 8, &lK[0][f0]);
    gload_lds16(kb + (size_t)row1 * 2048 + lch1 * 8, &lK[0][f1]);
    gload_lds16(vb + (size_t)row0 * T_ + lch0 * 8, &lVT[0][f0]);
    gload_lds16(vb + (size_t)row1 * T_ + lch1 * 8, &lVT[0][f1]);
  }
  int cur = 0;

  auto procPV = [&](f32x4* sA, const ushort_t* bufV, f32x4* accO,
                    f32x4& accL) {
#pragma unroll
    for (int ni = 0; ni < 4; ++ni) {
      float p0 = exp2f(sA[ni][0]);
      float p1 = exp2f(sA[ni][1]);
      float p2 = exp2f(sA[ni][2]);
      float p3 = exp2f(sA[ni][3]);
      unsigned lo = cvt_pk_bf16(p0, p1);
      unsigned hi = cvt_pk_bf16(p2, p3);
      int col = ni * 16 + r0;
#pragma unroll
      for (int r = 0; r < 4; ++r) {
        int rowp = rg + r;
        ushort_t hw = (r == 0)   ? (ushort_t)lo
                      : (r == 1) ? (ushort_t)(lo >> 16)
                      : (r == 2) ? (ushort_t)hi
                                 : (ushort_t)(hi >> 16);
        lPw[rowp * 64 + (col ^ ((rowp & 7) << 3))] = hw;
      }
    }
    __builtin_amdgcn_s_setprio(1);
#pragma unroll
    for (int kc = 0; kc < 2; ++kc) {
      int pch = (kc * 4 + p) ^ (r0 & 7);
      short8 aP = *(const short8*)&lPw[r0 * 64 + pch * 8];
      accL = __builtin_amdgcn_mfma_f32_16x16x32_bf16(aP, bOne, accL, 0, 0, 0);
#pragma unroll
      for (int ni = 0; ni < 4; ++ni) {
        int row = ni * 16 + r0;
        int ch = (kc * 4 + p) ^ (row & 7);
        short8 bV = *(const short8*)&bufV[row * 64 + ch * 8];
        accO[ni] =
            __builtin_amdgcn_mfma_f32_16x16x32_bf16(aP, bV, accO[ni], 0, 0, 0);
      }
    }
    __builtin_amdgcn_s_setprio(0);
  };

  for (int kt = 0; kt <= qb2; ++kt) {
    __syncthreads();

    if (kt < qb2) {
      const ushort_t* kb =
          qk + (size_t)(b * T_ + (kt + 1) * 64) * 2048 + 1024 + h * 64;
      const ushort_t* vb = Vt + (size_t)bh * 64 * (size_t)T_ + (kt + 1) * 64;
      ushort_t* dK = &lK[cur ^ 1][0];
      ushort_t* dV = &lVT[cur ^ 1][0];
      gload_lds16(kb + (size_t)row0 * 2048 + lch0 * 8, dK + f0);
      gload_lds16(kb + (size_t)row1 * 2048 + lch1 * 8, dK + f1);
      gload_lds16(vb + (size_t)row0 * T_ + lch0 * 8, dV + f0);
      gload_lds16(vb + (size_t)row1 * T_ + lch1 * 8, dV + f1);
    }

    const ushort_t* bufK = &lK[cur][0];
    const ushort_t* bufV = &lVT[cur][0];
    const bool act1 = (kt <= qb1);

    f32x4 sA2[4];
#pragma unroll
    for (int ni = 0; ni < 4; ++ni)
      sA2[ni] = f32x4{-16.f, -16.f, -16.f, -16.f};
    __builtin_amdgcn_s_setprio(1);
#pragma unroll
    for (int kc = 0; kc < 2; ++kc)
#pragma unroll
      for (int ni = 0; ni < 4; ++ni) {
        int row = ni * 16 + r0;
        int ch = (kc * 4 + p) ^ (row & 7);
        short8 bK = *(const short8*)&bufK[row * 64 + ch * 8];
        sA2[ni] =
            __builtin_amdgcn_mfma_f32_16x16x32_bf16(aQ2[kc], bK, sA2[ni], 0, 0, 0);
      }
    __builtin_amdgcn_s_setprio(0);
    if (kt == qb2) {
#pragma unroll
      for (int ni = 0; ni < 4; ++ni) {
        if (ni > w) {
#pragma unroll
          for (int r = 0; r < 4; ++r) sA2[ni][r] = -1e30f;
        } else if (ni == w) {
#pragma unroll
          for (int r = 0; r < 4; ++r)
            if (r0 > rg + r) sA2[ni][r] = -1e30f;
        }
      }
    }
    procPV(sA2, bufV, accO2, accL2);

    if (act1) {
      f32x4 sA1[4];
#pragma unroll
      for (int ni = 0; ni < 4; ++ni)
        sA1[ni] = f32x4{-16.f, -16.f, -16.f, -16.f};
      __builtin_amdgcn_s_setprio(1);
#pragma unroll
      for (int kc = 0; kc < 2; ++kc)
#pragma unroll
        for (int ni = 0; ni < 4; ++ni) {
          int row = ni * 16 + r0;
          int ch = (kc * 4 + p) ^ (row & 7);
          short8 bK = *(const short8*)&bufK[row * 64 + ch * 8];
          sA1[ni] = __builtin_amdgcn_mfma_f32_16x16x32_bf16(aQ1[kc], bK,
                                                            sA1[ni], 0, 0, 0);
        }
      __builtin_amdgcn_s_setprio(0);
      if (kt == qb1) {
#pragma unroll
        for (int ni = 0; ni < 4; ++ni) {
          if (ni > w) {
#pragma unroll
            for (int r = 0; r < 4; ++r) sA1[ni][r] = -1e30f;
          } else if (ni == w) {
#pragma unroll
            for (int r = 0; r < 4; ++r)
              if (r0 > rg + r) sA1[ni][r] = -1e30f;
          }
        }
      }
      procPV(sA1, bufV, accO1, accL1);
    }

    cur ^= 1;
  }

#pragma unroll
  for (int ni = 0; ni < 4; ++ni)
#pragma unroll
    for (int r = 0; r < 4; ++r) {
      int d = h * 64 + ni * 16 + r0;
      float v1 = accO1[ni][r] / accL1[r];
      float v2 = accO2[ni][r] / accL2[r];
      O[(size_t)(b * T_ + q1 + rg + r) * 1024 + d] = f2bf(v1);
      O[(size_t)(b * T_ + q2 + rg + r) * 1024 + d] = f2bf(v2);
    }
}

extern "C" void kernel_launch(void* const* d_in, const int* in_sizes, int n_in,
                              void* d_out, int out_size, void* d_ws, size_t ws_size,
                              hipStream_t stream) {
  const float* x = (const float*)d_in[0];
  const float* Wqkv = (const float*)d_in[1];
  const float* bqkv = (const float*)d_in[2];
  const float* Wproj = (const float*)d_in[3];
  const float* bproj = (const float*)d_in[4];
  float* out = (float*)d_out;

  ushort_t* xb = (ushort_t*)d_ws;                       // [8192][1024]
  ushort_t* wqkvb = xb + (size_t)M_ * D_;               // [3072][1024]
  ushort_t* wprojb = wqkvb + (size_t)3 * D_ * D_;       // [1024][1024]
  ushort_t* qkb = wprojb + (size_t)D_ * D_;             // [8192][2048] (Q|K)
  ushort_t* Vt = qkb + (size_t)M_ * 2048;               // [64][64][2048]
  ushort_t* Ob = Vt + (size_t)M_ * D_;                  // [8192][1024]

  f2bf3_kernel<<<2048, 256, 0, stream>>>(
      x, xb, M_ * D_ / 4,
      Wqkv, wqkvb, 3 * D_ * D_ / 4,
      Wproj, wprojb, D_ * D_ / 4);

  // QKV: (8192/256) * (3072/128) = 32*24 = 768 blocks (3 exact CU rounds)
  gemm256<true><<<768, 512, 0, stream>>>(
      xb, wqkvb, bqkv, qkb, Vt, M_, 3 * D_, D_, 2048);

  attn_kernel<<<dim3(16, 64), 256, 0, stream>>>(qkb, Vt, Ob);

  // proj: (8192/256) * (1024/128) = 32*8 = 256 blocks (1 exact CU round)
  gemm256<false><<<256, 512, 0, stream>>>(
      Ob, wprojb, bproj, out, nullptr, M_, D_, D_, D_);
}